// Round 5
// baseline (1161.017 us; speedup 1.0000x reference)
//
#include <hip/hip_runtime.h>
#include <cstdint>
#include <cstddef>

#define NQ 40000
#define EDIM 128
#define NVAL 43520
#define NCLS 21

typedef unsigned short u16;
typedef unsigned int uint;
typedef short bf16x8 __attribute__((ext_vector_type(8)));
typedef float f32x4 __attribute__((ext_vector_type(4)));

__device__ inline u16 f2b(float f) {
    unsigned u = __float_as_uint(f);
    unsigned r = u + 0x7FFF + ((u >> 16) & 1);
    return (u16)(r >> 16);
}
__device__ inline float b2f(u16 v) {
    unsigned u = ((unsigned)v) << 16;
    return __uint_as_float(u);
}
__device__ inline float blo(uint u) { return __uint_as_float(u << 16); }
__device__ inline float bhi(uint u) { return __uint_as_float(u & 0xFFFF0000u); }

// ---------------- mask ----------------
__global__ void reduce_max_int(const int* __restrict__ idx, int* __restrict__ mx) {
    int i = blockIdx.x * 256 + threadIdx.x;
    int v = (i < NQ) ? idx[i] : 0;
    for (int o = 32; o > 0; o >>= 1) v = max(v, __shfl_xor(v, o, 64));
    if ((threadIdx.x & 63) == 0) atomicMax(mx, v);
}

__global__ void write_mask(const int* __restrict__ idx, const int* __restrict__ mx,
                           float* __restrict__ out) {
    int i = blockIdx.x * 256 + threadIdx.x;
    if (i >= NQ) return;
    out[i] = (idx[i] < *mx) ? 1.0f : 0.0f;
}

// ---------------- conversions / packing ----------------
__global__ void cvt_b_k(const float* __restrict__ src, u16* __restrict__ dst, int n8) {
    int i = blockIdx.x * 256 + threadIdx.x;
    if (i >= n8) return;
    const float4 a = ((const float4*)src)[i * 2];
    const float4 b = ((const float4*)src)[i * 2 + 1];
    u16 o[8] = {f2b(a.x), f2b(a.y), f2b(a.z), f2b(a.w), f2b(b.x), f2b(b.y), f2b(b.z), f2b(b.w)};
    ((uint4*)dst)[i] = *(const uint4*)o;
}

__global__ void add2b_k(const float* __restrict__ a, const float* __restrict__ b,
                        u16* __restrict__ c, int n8) {
    int i = blockIdx.x * 256 + threadIdx.x;
    if (i >= n8) return;
    const float4 a0 = ((const float4*)a)[i * 2], a1 = ((const float4*)a)[i * 2 + 1];
    const float4 b0 = ((const float4*)b)[i * 2], b1 = ((const float4*)b)[i * 2 + 1];
    u16 o[8] = {f2b(a0.x + b0.x), f2b(a0.y + b0.y), f2b(a0.z + b0.z), f2b(a0.w + b0.w),
                f2b(a1.x + b1.x), f2b(a1.y + b1.y), f2b(a1.z + b1.z), f2b(a1.w + b1.w)};
    ((uint4*)c)[i] = *(const uint4*)o;
}

// fused encoder weight pack: all 6 matrices x 2 layers -> [n][128] bf16
__global__ void pack_enc_k(const float* __restrict__ Wv, const float* __restrict__ Woff,
                           const float* __restrict__ Wattn, const float* __restrict__ Wout,
                           const float* __restrict__ Wf1, const float* __restrict__ Wf2,
                           u16* __restrict__ dst) {
    int i = blockIdx.x * 256 + threadIdx.x;
    if (i >= 327680) return;
    int l = i / 163840, r = i % 163840;
    int k = r / 1280, col = r % 1280;
    const float* src; int N; int n; u16* d;
    u16* base = dst + (size_t)l * 163840;
    if (col < 128)       { src = Wv    + (size_t)l * 16384; N = 128; n = col;        d = base;          }
    else if (col < 640)  { src = Woff  + (size_t)l * 65536; N = 512; n = col - 128;  d = base + 16384;  }
    else if (col < 896)  { src = Wattn + (size_t)l * 32768; N = 256; n = col - 640;  d = base + 81920;  }
    else if (col < 1024) { src = Wout  + (size_t)l * 16384; N = 128; n = col - 896;  d = base + 114688; }
    else if (col < 1152) { src = Wf1   + (size_t)l * 16384; N = 128; n = col - 1024; d = base + 131072; }
    else                 { src = Wf2   + (size_t)l * 16384; N = 128; n = col - 1152; d = base + 147456; }
    d[(size_t)n * 128 + k] = f2b(src[(size_t)k * N + n]);
}

__global__ void pack_bias_k(const float* __restrict__ boff, const float* __restrict__ battn,
                            float* __restrict__ dst) {
    int i = blockIdx.x * 256 + threadIdx.x;
    if (i >= 1536) return;
    int l = i / 768, r = i % 768;
    dst[i] = (r < 512) ? boff[(size_t)l * 512 + r] : battn[(size_t)l * 256 + r - 512];
}

// cw [OC][IC][KS][KS] fp32 -> wT [KS*KS][OCp][ICp] bf16 (zero-padded)
__global__ void pack_cw_k(const float* __restrict__ w, u16* __restrict__ wT,
                          int OC, int IC, int KS, int OCp, int ICp) {
    int i = blockIdx.x * 256 + threadIdx.x;
    int tot = KS * KS * OCp * ICp;
    if (i >= tot) return;
    int ic = i % ICp; int r = i / ICp;
    int oc = r % OCp; int tap = r / OCp;
    int ky = tap / KS, kx = tap % KS;
    float v = 0.f;
    if (oc < OC && ic < IC)
        v = w[(((size_t)oc * IC + ic) * KS + ky) * KS + kx];
    wT[i] = f2b(v);
}

// ---------------- MFMA GEMM: C[M][N] = A[M][128] @ BT^T + bias ----------------
__global__ __launch_bounds__(256) void gemm_mfma_k(
        const u16* __restrict__ A, const u16* __restrict__ BT,
        const float* __restrict__ bias, float* __restrict__ Cf,
        u16* __restrict__ Cb, int N, int relu) {
    __shared__ u16 As[64 * 136];
    __shared__ u16 Bs[64 * 136];
    const int m0 = blockIdx.x * 64, n0 = blockIdx.y * 64;
    const int t = threadIdx.x;
#pragma unroll
    for (int ci = t; ci < 1024; ci += 256) {
        int r = ci >> 4, c = ci & 15;
        *(uint4*)&As[r * 136 + c * 8] = *(const uint4*)&A[(size_t)(m0 + r) * 128 + c * 8];
        *(uint4*)&Bs[r * 136 + c * 8] = *(const uint4*)&BT[(size_t)(n0 + r) * 128 + c * 8];
    }
    __syncthreads();
    const int wave = t >> 6, lane = t & 63;
    const int wm = (wave & 1) * 32, wn = (wave >> 1) * 32;
    const int lr = lane & 15, lk = (lane >> 4) * 8;
    f32x4 acc[2][2] = {};
#pragma unroll
    for (int ks = 0; ks < 4; ks++) {
        bf16x8 a0 = *(const bf16x8*)&As[(wm + lr) * 136 + ks * 32 + lk];
        bf16x8 a1 = *(const bf16x8*)&As[(wm + 16 + lr) * 136 + ks * 32 + lk];
        bf16x8 b0 = *(const bf16x8*)&Bs[(wn + lr) * 136 + ks * 32 + lk];
        bf16x8 b1 = *(const bf16x8*)&Bs[(wn + 16 + lr) * 136 + ks * 32 + lk];
        acc[0][0] = __builtin_amdgcn_mfma_f32_16x16x32_bf16(a0, b0, acc[0][0], 0, 0, 0);
        acc[0][1] = __builtin_amdgcn_mfma_f32_16x16x32_bf16(a0, b1, acc[0][1], 0, 0, 0);
        acc[1][0] = __builtin_amdgcn_mfma_f32_16x16x32_bf16(a1, b0, acc[1][0], 0, 0, 0);
        acc[1][1] = __builtin_amdgcn_mfma_f32_16x16x32_bf16(a1, b1, acc[1][1], 0, 0, 0);
    }
    float bj0 = bias[n0 + wn + lr];
    float bj1 = bias[n0 + wn + 16 + lr];
#pragma unroll
    for (int i = 0; i < 2; i++) {
#pragma unroll
        for (int j = 0; j < 2; j++) {
            float bb = j ? bj1 : bj0;
#pragma unroll
            for (int r = 0; r < 4; r++) {
                int ml = wm + i * 16 + (lane >> 4) * 4 + r;
                int nl = wn + j * 16 + lr;
                float v = acc[i][j][r] + bb;
                if (relu) v = fmaxf(v, 0.f);
                size_t o = (size_t)(m0 + ml) * N + n0 + nl;
                if (Cf) Cf[o] = v;
                if (Cb) Cb[o] = f2b(v);
            }
        }
    }
}

// ---------------- conv: 64px (1 row) x 64 OC, explicit register-B double buffer ----------------
// pimg: padded [206][208][ICP] bf16 (3px frame, zeroed)
// wT: [KS*KS][OCtot][ICP] bf16 ; out: [40000][OCtot] fp32
template <int KS, int ICP>
__global__ __launch_bounds__(256) void conv4_mfma_k(
        const u16* __restrict__ pimg, const u16* __restrict__ wT,
        float* __restrict__ out, int OCtot) {
    constexpr int PAD = KS / 2;
    constexpr int WIN = 64 + KS - 1;
    constexpr int LDSTR = ICP + 8;
    constexpr int KSTEPS = ICP / 32;
    constexpr int NTAP = KS * KS;
    __shared__ u16 As[WIN * LDSTR];
    const int bx = blockIdx.x;
    const int y = bx >> 2;
    const int xc = bx & 3;
    const int x0 = (xc == 3) ? 136 : xc * 64;
    const int n0 = blockIdx.y * 64;
    const int t = threadIdx.x;
    const int wave = t >> 6, lane = t & 63;
    const int wm = (wave & 1) * 32, wn = (wave >> 1) * 32;
    const int lr = lane & 15, lkq = lane >> 4, lk = lkq * 8;

    f32x4 acc[2][2] = {};
    const u16* wbase = wT + (size_t)n0 * ICP;

    bf16x8 cur0[KSTEPS], cur1[KSTEPS], nxt0[KSTEPS], nxt1[KSTEPS];
    // load tap 0
#pragma unroll
    for (int ks = 0; ks < KSTEPS; ks++) {
        cur0[ks] = *(const bf16x8*)&wbase[(size_t)(wn + lr) * ICP + ks * 32 + lk];
        cur1[ks] = *(const bf16x8*)&wbase[(size_t)(wn + 16 + lr) * ICP + ks * 32 + lk];
    }

    for (int ky = 0; ky < KS; ky++) {
        __syncthreads();
        const u16* src = pimg + (((size_t)(y + ky + 3 - PAD)) * 208 + (x0 + 3 - PAD)) * ICP;
        for (int ci = t; ci < WIN * (ICP / 8); ci += 256) {
            int r = ci / (ICP / 8), c = ci - r * (ICP / 8);
            *(uint4*)&As[r * LDSTR + c * 8] = *(const uint4*)&src[(size_t)r * ICP + c * 8];
        }
        __syncthreads();
#pragma unroll
        for (int kx = 0; kx < KS; kx++) {
            const int tap = ky * KS + kx;
            if (tap + 1 < NTAP) {
                const u16* wb = wbase + (size_t)(tap + 1) * OCtot * ICP;
#pragma unroll
                for (int ks = 0; ks < KSTEPS; ks++) {
                    nxt0[ks] = *(const bf16x8*)&wb[(size_t)(wn + lr) * ICP + ks * 32 + lk];
                    nxt1[ks] = *(const bf16x8*)&wb[(size_t)(wn + 16 + lr) * ICP + ks * 32 + lk];
                }
            }
#pragma unroll
            for (int ks = 0; ks < KSTEPS; ks++) {
                bf16x8 a0 = *(const bf16x8*)&As[(wm + lr + kx) * LDSTR + ks * 32 + lk];
                bf16x8 a1 = *(const bf16x8*)&As[(wm + 16 + lr + kx) * LDSTR + ks * 32 + lk];
                acc[0][0] = __builtin_amdgcn_mfma_f32_16x16x32_bf16(a0, cur0[ks], acc[0][0], 0, 0, 0);
                acc[0][1] = __builtin_amdgcn_mfma_f32_16x16x32_bf16(a0, cur1[ks], acc[0][1], 0, 0, 0);
                acc[1][0] = __builtin_amdgcn_mfma_f32_16x16x32_bf16(a1, cur0[ks], acc[1][0], 0, 0, 0);
                acc[1][1] = __builtin_amdgcn_mfma_f32_16x16x32_bf16(a1, cur1[ks], acc[1][1], 0, 0, 0);
            }
#pragma unroll
            for (int ks = 0; ks < KSTEPS; ks++) { cur0[ks] = nxt0[ks]; cur1[ks] = nxt1[ks]; }
        }
    }
    const int px0 = y * 200 + x0;
#pragma unroll
    for (int i = 0; i < 2; i++) {
#pragma unroll
        for (int j = 0; j < 2; j++) {
#pragma unroll
            for (int r = 0; r < 4; r++) {
                int ml = wm + i * 16 + lkq * 4 + r;
                int nl = wn + j * 16 + lr;
                out[(size_t)(px0 + ml) * OCtot + n0 + nl] = acc[i][j][r];
            }
        }
    }
}

// ---------------- deformable sampling: 2 queries per wave, uint2 gathers ----------------
// v [NVAL][128] bf16, oa [nq][768] bf16 (512 offsets + 256 logits), out [NQ][128] bf16
__global__ __launch_bounds__(256) void deform3_k(
        const u16* __restrict__ v, const u16* __restrict__ oa,
        u16* __restrict__ outb, int q0, int nq) {
    const int t = threadIdx.x;
    const int wq = t >> 6;
    const int lane = t & 63;
    const int s = lane >> 5;
    const int l32 = lane & 31;
    const int h = l32 >> 2;      // head 0..7
    const int cl = l32 & 3;      // 4 channels each (cl*4)
    const int qi = blockIdx.x * 8 + wq * 2 + s;
    if (qi >= nq) return;
    const int gq = q0 + qi;
    const float rx = ((gq % 200) + 0.5f) / 200.f;
    const float ry = ((gq / 200) + 0.5f) / 200.f;

    const uint* lp = (const uint*)(oa + (size_t)qi * 768 + 512 + h * 32);
    float lg[32];
#pragma unroll
    for (int i = 0; i < 16; i++) { uint u = lp[i]; lg[2 * i] = blo(u); lg[2 * i + 1] = bhi(u); }
    float mx = -1e30f;
#pragma unroll
    for (int i = 0; i < 32; i++) mx = fmaxf(mx, lg[i]);
    float ssum = 0.f;
#pragma unroll
    for (int i = 0; i < 32; i++) { lg[i] = __expf(lg[i] - mx); ssum += lg[i]; }
    const float inv = 1.f / ssum;

    const uint* op = (const uint*)(oa + (size_t)qi * 768 + h * 64);

    const int HS[4] = {128, 64, 32, 16};
    const int WS[4] = {256, 128, 64, 32};
    const int ST[4] = {0, 32768, 40960, 43008};
    float a0 = 0.f, a1 = 0.f, a2 = 0.f, a3 = 0.f;
#pragma unroll
    for (int l = 0; l < 4; l++) {
        const int H = HS[l], W = WS[l];
        const float fW = (float)W, fH = (float)H;
        const u16* vb = v + (size_t)ST[l] * 128 + h * 16 + cl * 4;
#pragma unroll
        for (int p = 0; p < 8; p++) {
            uint pr = op[l * 8 + p];
            float ox = blo(pr), oy = bhi(pr);
            float xx = rx * fW + ox - 0.5f;
            float yy = ry * fH + oy - 0.5f;
            float xf = floorf(xx), yf = floorf(yy);
            int ix = (int)xf, iy = (int)yf;
            float fx = xx - xf, fy = yy - yf;
            float aw = lg[l * 8 + p] * inv;
            int x1 = ix + 1, y1 = iy + 1;
            bool vx0 = (unsigned)ix < (unsigned)W;
            bool vx1 = (unsigned)x1 < (unsigned)W;
            bool vy0 = (unsigned)iy < (unsigned)H;
            bool vy1 = (unsigned)y1 < (unsigned)H;
            int cx0 = min(max(ix, 0), W - 1), cx1 = min(max(x1, 0), W - 1);
            int cy0 = min(max(iy, 0), H - 1), cy1 = min(max(y1, 0), H - 1);
            float w00 = (vx0 && vy0) ? (1.f - fx) * (1.f - fy) * aw : 0.f;
            float w10 = (vx1 && vy0) ? fx * (1.f - fy) * aw : 0.f;
            float w01 = (vx0 && vy1) ? (1.f - fx) * fy * aw : 0.f;
            float w11 = (vx1 && vy1) ? fx * fy * aw : 0.f;
            uint2 u00 = *(const uint2*)(vb + (size_t)(cy0 * W + cx0) * 128);
            uint2 u10 = *(const uint2*)(vb + (size_t)(cy0 * W + cx1) * 128);
            uint2 u01 = *(const uint2*)(vb + (size_t)(cy1 * W + cx0) * 128);
            uint2 u11 = *(const uint2*)(vb + (size_t)(cy1 * W + cx1) * 128);
            a0 = fmaf(w00, blo(u00.x), a0); a1 = fmaf(w00, bhi(u00.x), a1);
            a2 = fmaf(w00, blo(u00.y), a2); a3 = fmaf(w00, bhi(u00.y), a3);
            a0 = fmaf(w10, blo(u10.x), a0); a1 = fmaf(w10, bhi(u10.x), a1);
            a2 = fmaf(w10, blo(u10.y), a2); a3 = fmaf(w10, bhi(u10.y), a3);
            a0 = fmaf(w01, blo(u01.x), a0); a1 = fmaf(w01, bhi(u01.x), a1);
            a2 = fmaf(w01, blo(u01.y), a2); a3 = fmaf(w01, bhi(u01.y), a3);
            a0 = fmaf(w11, blo(u11.x), a0); a1 = fmaf(w11, bhi(u11.x), a1);
            a2 = fmaf(w11, blo(u11.y), a2); a3 = fmaf(w11, bhi(u11.y), a3);
        }
    }
    uint2 o;
    o.x = (uint)f2b(a0) | ((uint)f2b(a1) << 16);
    o.y = (uint)f2b(a2) | ((uint)f2b(a3) << 16);
    *(uint2*)(outb + (size_t)gq * 128 + h * 16 + cl * 4) = o;
}

// ---------------- fused residual + layernorm ----------------
__global__ __launch_bounds__(256) void add_ln_k(
        float* __restrict__ q, const float* __restrict__ a,
        const float* __restrict__ g, const float* __restrict__ b,
        u16* __restrict__ qb) {
    const int row = blockIdx.x * 4 + (threadIdx.x >> 6);
    const int lane = threadIdx.x & 63;
    float s0 = q[(size_t)row * 128 + lane] + a[(size_t)row * 128 + lane];
    float s1 = q[(size_t)row * 128 + 64 + lane] + a[(size_t)row * 128 + 64 + lane];
    float sum = s0 + s1;
    for (int o = 32; o > 0; o >>= 1) sum += __shfl_xor(sum, o, 64);
    float mean = sum * (1.f / 128.f);
    float d0 = s0 - mean, d1 = s1 - mean;
    float vs = d0 * d0 + d1 * d1;
    for (int o = 32; o > 0; o >>= 1) vs += __shfl_xor(vs, o, 64);
    float inv = rsqrtf(vs * (1.f / 128.f) + 1e-5f);
    float o0 = d0 * inv * g[lane] + b[lane];
    float o1 = d1 * inv * g[64 + lane] + b[64 + lane];
    q[(size_t)row * 128 + lane] = o0;
    q[(size_t)row * 128 + 64 + lane] = o1;
    qb[(size_t)row * 128 + lane] = f2b(o0);
    qb[(size_t)row * 128 + 64 + lane] = f2b(o1);
}

// ---------------- pimg fill from qb (128 ch), covers borders with zero ----------------
__global__ void fill_pimg2_k(const u16* __restrict__ qb, u16* __restrict__ pimg) {
    int i = blockIdx.x * 256 + threadIdx.x;   // over 206*208*16 uint4
    if (i >= 685568) return;
    int pp = i >> 4, c8 = i & 15;
    int py = pp / 208, px = pp - py * 208;
    uint4 val = {0u, 0u, 0u, 0u};
    if (py >= 3 && py < 203 && px >= 3 && px < 203)
        val = ((const uint4*)qb)[((size_t)((py - 3) * 200 + (px - 3))) * 16 + c8];
    ((uint4*)pimg)[i] = val;
}

// ---------------- BN stats + apply ----------------
__global__ __launch_bounds__(256) void bn_stats2_k(const float* __restrict__ x,
                                                   float* __restrict__ acc,
                                                   int cSh, int ppb) {
    const int t = threadIdx.x;
    const int Cp = 1 << cSh;
    const int c = t & (Cp - 1);
    const int sub = t >> cSh;
    const int nsub = 256 >> cSh;
    float s = 0.f, s2 = 0.f;
    const int pbase = blockIdx.x * ppb;
    for (int i = sub; i < ppb; i += nsub) {
        float v = x[(size_t)(pbase + i) * Cp + c];
        s += v; s2 += v * v;
    }
    __shared__ float ls[256], ls2[256];
    ls[t] = s; ls2[t] = s2;
    __syncthreads();
    if (t < Cp) {
        for (int k = 1; k < nsub; k++) { s += ls[t + k * Cp]; s2 += ls2[t + k * Cp]; }
        atomicAdd(&acc[2 * t], s);
        atomicAdd(&acc[2 * t + 1], s2);
    }
}

__global__ void bn_fin_k(const float* __restrict__ acc, float* __restrict__ mv, int C) {
    int t = threadIdx.x;
    if (t >= C) return;
    float m = acc[2 * t] * (1.f / 40000.f);
    float var = acc[2 * t + 1] * (1.f / 40000.f) - m * m;
    mv[2 * t] = m;
    mv[2 * t + 1] = rsqrtf(var + 1e-5f);
}

// apply into padded image layout, writing zeros on borders (no pre-memset needed)
__global__ void bn_apply_pad2_k(const float* __restrict__ x, const float* __restrict__ mv,
                                const float* __restrict__ g, const float* __restrict__ b,
                                u16* __restrict__ outp, int cSh, int Creal) {
    int i = blockIdx.x * 256 + threadIdx.x;
    int Cp = 1 << cSh;
    if (i >= 206 * 208 * Cp) return;
    int c = i & (Cp - 1);
    int pp = i >> cSh;
    int py = pp / 208, px = pp - py * 208;
    float v = 0.f;
    if (c < Creal && py >= 3 && py < 203 && px >= 3 && px < 203) {
        int p = (py - 3) * 200 + (px - 3);
        v = fmaxf((x[(size_t)p * Cp + c] - mv[2 * c]) * mv[2 * c + 1] * g[c] + b[c], 0.f);
    }
    outp[i] = f2b(v);
}

// apply into plain [p][Cp] layout (final stage feeding the 1x1 head)
__global__ void bn_apply2_k(const float* __restrict__ x, const float* __restrict__ mv,
                            const float* __restrict__ g, const float* __restrict__ b,
                            u16* __restrict__ outb, int cSh, int Creal) {
    int i = blockIdx.x * 256 + threadIdx.x;
    int Cp = 1 << cSh;
    if (i >= 40000 * Cp) return;
    int c = i & (Cp - 1);
    float v = 0.f;
    if (c < Creal) v = fmaxf((x[i] - mv[2 * c]) * mv[2 * c + 1] * g[c] + b[c], 0.f);
    outb[i] = f2b(v);
}

// ---------------- 1x1 obj head ----------------
__global__ void obj_conv_k(const u16* __restrict__ in, const float* __restrict__ w,
                           const float* __restrict__ bias, float* __restrict__ out) {
    int p = blockIdx.x * 256 + threadIdx.x;
    if (p >= 40000) return;
    float xin[48];
#pragma unroll
    for (int c = 0; c < 48; c++) xin[c] = b2f(in[(size_t)p * 64 + c]);
    for (int o = 0; o < NCLS; o++) {
        float acc = bias[o];
#pragma unroll
        for (int c = 0; c < 48; c++) acc += xin[c] * w[o * 48 + c];
        out[(size_t)o * 40000 + p] = acc;
    }
}

extern "C" void kernel_launch(void* const* d_in, const int* in_sizes, int n_in,
                              void* d_out, int out_size, void* d_ws, size_t ws_size,
                              hipStream_t stream) {
    const float* value   = (const float*)d_in[0];
    const float* bev_q   = (const float*)d_in[1];
    const float* bev_pos = (const float*)d_in[2];
    const int*   proj    = (const int*)d_in[3];
    const float* Wv      = (const float*)d_in[4];
    const float* bv      = (const float*)d_in[5];
    const float* Woff    = (const float*)d_in[6];
    const float* boff    = (const float*)d_in[7];
    const float* Wattn   = (const float*)d_in[8];
    const float* battn   = (const float*)d_in[9];
    const float* Wout    = (const float*)d_in[10];
    const float* bout    = (const float*)d_in[11];
    const float* Wf1     = (const float*)d_in[12];
    const float* bf1     = (const float*)d_in[13];
    const float* Wf2     = (const float*)d_in[14];
    const float* bf2     = (const float*)d_in[15];
    const float* ln_g    = (const float*)d_in[16];
    const float* ln_b    = (const float*)d_in[17];
    const float* cw1     = (const float*)d_in[18];
    const float* g1      = (const float*)d_in[19];
    const float* b1      = (const float*)d_in[20];
    const float* cw2     = (const float*)d_in[21];
    const float* g2      = (const float*)d_in[22];
    const float* b2      = (const float*)d_in[23];
    const float* cw3     = (const float*)d_in[24];
    const float* g3      = (const float*)d_in[25];
    const float* b3      = (const float*)d_in[26];
    const float* cw4     = (const float*)d_in[27];
    const float* g4      = (const float*)d_in[28];
    const float* b4      = (const float*)d_in[29];
    const float* objw    = (const float*)d_in[30];
    const float* objb    = (const float*)d_in[31];
    float* out = (float*)d_out;

    float* WSb = (float*)d_ws;
    // encoder-stage layout (float-unit offsets)
    float* q     = WSb + 0;                        // 5,120,000
    u16*   qb    = (u16*)(WSb + 5120000);          // 2,560,000 f
    u16*   qpb   = (u16*)(WSb + 7680000);          // 2,560,000 f
    u16*   valb  = (u16*)(WSb + 10240000);         // 2,785,280 f
    u16*   vbufb = (u16*)(WSb + 13025280);         // 2,785,280 f
    u16*   fb    = (u16*)(WSb + 15810560);         // fused off+attn [20032][768] bf16
    float* tmp   = WSb + 18882560;                 // 5,120,000 f (time-disjoint with fb)
    u16*   aob   = (u16*)(WSb + 24002560);         // 2,560,000 f
    u16*   hb    = (u16*)(WSb + 26562560);         // 2,560,000 f
    u16*   wenc  = (u16*)(WSb + 29122560);         // 163,840 f
    u16*   wcv   = (u16*)(WSb + 29286400);         // 475,136 f
    float* bnacc = WSb + 29761536;                 // 512
    float* bnmv  = WSb + 29762048;                 // 256
    int*   maxi  = (int*)(WSb + 29762304);
    float* fbias = WSb + 29762308;                 // 1536

    // conv-stage aliases
    u16*   pimg = (u16*)(WSb + 10240000);          // padded 206x208x128 (over valb)
    float* c1f  = tmp;
    u16*   c1b  = (u16*)(WSb + 13025280);          // padded 206x208x128 (over vbufb)
    float* c2f  = WSb + 0;
    u16*   c2b  = (u16*)(WSb + 5120000);           // padded 206x208x64 (over qb)
    float* c3f  = WSb + 2560000;
    u16*   c3b  = (u16*)(WSb + 7680000);           // padded 206x208x64 (over qpb)
    float* c4f  = WSb + 0;
    u16*   c4b  = (u16*)(WSb + 15810560);          // [40000][64] plain (over fb)

    const size_t L = 163840;
    u16* WvT[2]; u16* WoffT[2]; u16* WoutT[2]; u16* Wf1T[2]; u16* Wf2T[2];
    for (int l = 0; l < 2; l++) {
        u16* base = wenc + l * L;
        WvT[l]    = base;
        WoffT[l]  = base + 16384;   // rows 0..511 = Woff, 512..767 = Wattn
        WoutT[l]  = base + 114688;
        Wf1T[l]   = base + 131072;
        Wf2T[l]   = base + 147456;
    }
    u16* w1T = wcv;
    u16* w2T = wcv + 802816;
    u16* w3T = wcv + 876544;
    u16* w4T = wcv + 913408;

    // ---- mask ----
    hipMemsetAsync(maxi, 0, sizeof(int), stream);
    reduce_max_int<<<157, 256, 0, stream>>>(proj, maxi);
    write_mask<<<157, 256, 0, stream>>>(proj, maxi, out + 840000);

    // ---- weight packing ----
    pack_enc_k<<<1280, 256, 0, stream>>>(Wv, Woff, Wattn, Wout, Wf1, Wf2, wenc);
    pack_bias_k<<<6, 256, 0, stream>>>(boff, battn, fbias);
    pack_cw_k<<<3136, 256, 0, stream>>>(cw1, w1T, 128, 128, 7, 128, 128);
    pack_cw_k<<<288, 256, 0, stream>>>(cw2, w2T, 64, 128, 3, 64, 128);
    pack_cw_k<<<144, 256, 0, stream>>>(cw3, w3T, 48, 64, 3, 64, 64);
    pack_cw_k<<<144, 256, 0, stream>>>(cw4, w4T, 48, 48, 3, 64, 64);
    cvt_b_k<<<2720, 256, 0, stream>>>(value, valb, NVAL * 128 / 8);

    // ---- encoder ----
    hipMemcpyAsync(q, bev_q, (size_t)NQ * EDIM * sizeof(float),
                   hipMemcpyDeviceToDevice, stream);
    const int CH0 = 19968, CH1 = 20032;
    for (int l = 0; l < 2; l++) {
        gemm_mfma_k<<<dim3(680, 2), 256, 0, stream>>>(
            valb, WvT[l], bv + (size_t)l * 128, nullptr, vbufb, 128, 0);
        add2b_k<<<2500, 256, 0, stream>>>(q, bev_pos, qpb, NQ * 128 / 8);
        for (int cidx = 0; cidx < 2; cidx++) {
            int qs = cidx ? CH0 : 0;
            int nq = cidx ? CH1 : CH0;
            gemm_mfma_k<<<dim3(nq / 64, 12), 256, 0, stream>>>(
                qpb + (size_t)qs * 128, WoffT[l], fbias + (size_t)l * 768,
                nullptr, fb, 768, 0);
            deform3_k<<<nq / 8, 256, 0, stream>>>(vbufb, fb, aob, qs, nq);
        }
        gemm_mfma_k<<<dim3(625, 2), 256, 0, stream>>>(
            aob, WoutT[l], bout + (size_t)l * 128, tmp, nullptr, 128, 0);
        add_ln_k<<<10000, 256, 0, stream>>>(q, tmp, ln_g + (size_t)(l * 2 + 0) * 128,
                                            ln_b + (size_t)(l * 2 + 0) * 128, qb);
        gemm_mfma_k<<<dim3(625, 2), 256, 0, stream>>>(
            qb, Wf1T[l], bf1 + (size_t)l * 128, nullptr, hb, 128, 1);
        gemm_mfma_k<<<dim3(625, 2), 256, 0, stream>>>(
            hb, Wf2T[l], bf2 + (size_t)l * 128, tmp, nullptr, 128, 0);
        add_ln_k<<<10000, 256, 0, stream>>>(q, tmp, ln_g + (size_t)(l * 2 + 1) * 128,
                                            ln_b + (size_t)(l * 2 + 1) * 128, qb);
    }

    // ---- conv head ----
    fill_pimg2_k<<<2678, 256, 0, stream>>>(qb, pimg);

    conv4_mfma_k<7, 128><<<dim3(800, 2), 256, 0, stream>>>(pimg, w1T, c1f, 128);
    hipMemsetAsync(bnacc, 0, 512 * sizeof(float), stream);
    bn_stats2_k<<<125, 256, 0, stream>>>(c1f, bnacc, 7, 320);
    bn_fin_k<<<1, 128, 0, stream>>>(bnacc, bnmv, 128);
    bn_apply_pad2_k<<<21424, 256, 0, stream>>>(c1f, bnmv, g1, b1, c1b, 7, 128);

    conv4_mfma_k<3, 128><<<dim3(800, 1), 256, 0, stream>>>(c1b, w2T, c2f, 64);
    hipMemsetAsync(bnacc, 0, 512 * sizeof(float), stream);
    bn_stats2_k<<<125, 256, 0, stream>>>(c2f, bnacc, 6, 320);
    bn_fin_k<<<1, 64, 0, stream>>>(bnacc, bnmv, 64);
    bn_apply_pad2_k<<<10712, 256, 0, stream>>>(c2f, bnmv, g2, b2, c2b, 6, 64);

    conv4_mfma_k<3, 64><<<dim3(800, 1), 256, 0, stream>>>(c2b, w3T, c3f, 64);
    hipMemsetAsync(bnacc, 0, 512 * sizeof(float), stream);
    bn_stats2_k<<<125, 256, 0, stream>>>(c3f, bnacc, 6, 320);
    bn_fin_k<<<1, 48, 0, stream>>>(bnacc, bnmv, 48);
    bn_apply_pad2_k<<<10712, 256, 0, stream>>>(c3f, bnmv, g3, b3, c3b, 6, 48);

    conv4_mfma_k<3, 64><<<dim3(800, 1), 256, 0, stream>>>(c3b, w4T, c4f, 64);
    hipMemsetAsync(bnacc, 0, 512 * sizeof(float), stream);
    bn_stats2_k<<<125, 256, 0, stream>>>(c4f, bnacc, 6, 320);
    bn_fin_k<<<1, 48, 0, stream>>>(bnacc, bnmv, 48);
    bn_apply2_k<<<10000, 256, 0, stream>>>(c4f, bnmv, g4, b4, c4b, 6, 48);

    obj_conv_k<<<157, 256, 0, stream>>>(c4b, objw, objb, out);
}

// Round 6
// 1023.768 us; speedup vs baseline: 1.1341x; 1.1341x over previous
//
#include <hip/hip_runtime.h>
#include <cstdint>
#include <cstddef>

#define NQ 40000
#define EDIM 128
#define NVAL 43520
#define NCLS 21

typedef unsigned short u16;
typedef unsigned int uint;
typedef short bf16x8 __attribute__((ext_vector_type(8)));
typedef float f32x4 __attribute__((ext_vector_type(4)));

__device__ inline u16 f2b(float f) {
    unsigned u = __float_as_uint(f);
    unsigned r = u + 0x7FFF + ((u >> 16) & 1);
    return (u16)(r >> 16);
}
__device__ inline float b2f(u16 v) {
    unsigned u = ((unsigned)v) << 16;
    return __uint_as_float(u);
}
__device__ inline float blo(uint u) { return __uint_as_float(u << 16); }
__device__ inline float bhi(uint u) { return __uint_as_float(u & 0xFFFF0000u); }

// ---------------- mask ----------------
__global__ void reduce_max_int(const int* __restrict__ idx, int* __restrict__ mx) {
    int i = blockIdx.x * 256 + threadIdx.x;
    int v = (i < NQ) ? idx[i] : 0;
    for (int o = 32; o > 0; o >>= 1) v = max(v, __shfl_xor(v, o, 64));
    if ((threadIdx.x & 63) == 0) atomicMax(mx, v);
}

__global__ void write_mask(const int* __restrict__ idx, const int* __restrict__ mx,
                           float* __restrict__ out) {
    int i = blockIdx.x * 256 + threadIdx.x;
    if (i >= NQ) return;
    out[i] = (idx[i] < *mx) ? 1.0f : 0.0f;
}

// ---------------- conversions / packing ----------------
__global__ void cvt_b_k(const float* __restrict__ src, u16* __restrict__ dst, int n8) {
    int i = blockIdx.x * 256 + threadIdx.x;
    if (i >= n8) return;
    const float4 a = ((const float4*)src)[i * 2];
    const float4 b = ((const float4*)src)[i * 2 + 1];
    u16 o[8] = {f2b(a.x), f2b(a.y), f2b(a.z), f2b(a.w), f2b(b.x), f2b(b.y), f2b(b.z), f2b(b.w)};
    ((uint4*)dst)[i] = *(const uint4*)o;
}

__global__ void add2b_k(const float* __restrict__ a, const float* __restrict__ b,
                        u16* __restrict__ c, int n8) {
    int i = blockIdx.x * 256 + threadIdx.x;
    if (i >= n8) return;
    const float4 a0 = ((const float4*)a)[i * 2], a1 = ((const float4*)a)[i * 2 + 1];
    const float4 b0 = ((const float4*)b)[i * 2], b1 = ((const float4*)b)[i * 2 + 1];
    u16 o[8] = {f2b(a0.x + b0.x), f2b(a0.y + b0.y), f2b(a0.z + b0.z), f2b(a0.w + b0.w),
                f2b(a1.x + b1.x), f2b(a1.y + b1.y), f2b(a1.z + b1.z), f2b(a1.w + b1.w)};
    ((uint4*)c)[i] = *(const uint4*)o;
}

// fused encoder weight pack: all 6 matrices x 2 layers -> [n][128] bf16
__global__ void pack_enc_k(const float* __restrict__ Wv, const float* __restrict__ Woff,
                           const float* __restrict__ Wattn, const float* __restrict__ Wout,
                           const float* __restrict__ Wf1, const float* __restrict__ Wf2,
                           u16* __restrict__ dst) {
    int i = blockIdx.x * 256 + threadIdx.x;
    if (i >= 327680) return;
    int l = i / 163840, r = i % 163840;
    int k = r / 1280, col = r % 1280;
    const float* src; int N; int n; u16* d;
    u16* base = dst + (size_t)l * 163840;
    if (col < 128)       { src = Wv    + (size_t)l * 16384; N = 128; n = col;        d = base;          }
    else if (col < 640)  { src = Woff  + (size_t)l * 65536; N = 512; n = col - 128;  d = base + 16384;  }
    else if (col < 896)  { src = Wattn + (size_t)l * 32768; N = 256; n = col - 640;  d = base + 81920;  }
    else if (col < 1024) { src = Wout  + (size_t)l * 16384; N = 128; n = col - 896;  d = base + 114688; }
    else if (col < 1152) { src = Wf1   + (size_t)l * 16384; N = 128; n = col - 1024; d = base + 131072; }
    else                 { src = Wf2   + (size_t)l * 16384; N = 128; n = col - 1152; d = base + 147456; }
    d[(size_t)n * 128 + k] = f2b(src[(size_t)k * N + n]);
}

__global__ void pack_bias_k(const float* __restrict__ boff, const float* __restrict__ battn,
                            float* __restrict__ dst) {
    int i = blockIdx.x * 256 + threadIdx.x;
    if (i >= 1536) return;
    int l = i / 768, r = i % 768;
    dst[i] = (r < 512) ? boff[(size_t)l * 512 + r] : battn[(size_t)l * 256 + r - 512];
}

// cw [OC][IC][KS][KS] fp32 -> wT [KS*KS][OCp][ICp] bf16 (zero-padded)
__global__ void pack_cw_k(const float* __restrict__ w, u16* __restrict__ wT,
                          int OC, int IC, int KS, int OCp, int ICp) {
    int i = blockIdx.x * 256 + threadIdx.x;
    int tot = KS * KS * OCp * ICp;
    if (i >= tot) return;
    int ic = i % ICp; int r = i / ICp;
    int oc = r % OCp; int tap = r / OCp;
    int ky = tap / KS, kx = tap % KS;
    float v = 0.f;
    if (oc < OC && ic < IC)
        v = w[(((size_t)oc * IC + ic) * KS + ky) * KS + kx];
    wT[i] = f2b(v);
}

// ---------------- MFMA GEMM: C[M][N] = A[M][128] @ BT^T + bias ----------------
__global__ __launch_bounds__(256) void gemm_mfma_k(
        const u16* __restrict__ A, const u16* __restrict__ BT,
        const float* __restrict__ bias, float* __restrict__ Cf,
        u16* __restrict__ Cb, int N, int relu) {
    __shared__ u16 As[64 * 136];
    __shared__ u16 Bs[64 * 136];
    const int m0 = blockIdx.x * 64, n0 = blockIdx.y * 64;
    const int t = threadIdx.x;
#pragma unroll
    for (int ci = t; ci < 1024; ci += 256) {
        int r = ci >> 4, c = ci & 15;
        *(uint4*)&As[r * 136 + c * 8] = *(const uint4*)&A[(size_t)(m0 + r) * 128 + c * 8];
        *(uint4*)&Bs[r * 136 + c * 8] = *(const uint4*)&BT[(size_t)(n0 + r) * 128 + c * 8];
    }
    __syncthreads();
    const int wave = t >> 6, lane = t & 63;
    const int wm = (wave & 1) * 32, wn = (wave >> 1) * 32;
    const int lr = lane & 15, lk = (lane >> 4) * 8;
    f32x4 acc[2][2] = {};
#pragma unroll
    for (int ks = 0; ks < 4; ks++) {
        bf16x8 a0 = *(const bf16x8*)&As[(wm + lr) * 136 + ks * 32 + lk];
        bf16x8 a1 = *(const bf16x8*)&As[(wm + 16 + lr) * 136 + ks * 32 + lk];
        bf16x8 b0 = *(const bf16x8*)&Bs[(wn + lr) * 136 + ks * 32 + lk];
        bf16x8 b1 = *(const bf16x8*)&Bs[(wn + 16 + lr) * 136 + ks * 32 + lk];
        acc[0][0] = __builtin_amdgcn_mfma_f32_16x16x32_bf16(a0, b0, acc[0][0], 0, 0, 0);
        acc[0][1] = __builtin_amdgcn_mfma_f32_16x16x32_bf16(a0, b1, acc[0][1], 0, 0, 0);
        acc[1][0] = __builtin_amdgcn_mfma_f32_16x16x32_bf16(a1, b0, acc[1][0], 0, 0, 0);
        acc[1][1] = __builtin_amdgcn_mfma_f32_16x16x32_bf16(a1, b1, acc[1][1], 0, 0, 0);
    }
    float bj0 = bias[n0 + wn + lr];
    float bj1 = bias[n0 + wn + 16 + lr];
#pragma unroll
    for (int i = 0; i < 2; i++) {
#pragma unroll
        for (int j = 0; j < 2; j++) {
            float bb = j ? bj1 : bj0;
#pragma unroll
            for (int r = 0; r < 4; r++) {
                int ml = wm + i * 16 + (lane >> 4) * 4 + r;
                int nl = wn + j * 16 + lr;
                float v = acc[i][j][r] + bb;
                if (relu) v = fmaxf(v, 0.f);
                size_t o = (size_t)(m0 + ml) * N + n0 + nl;
                if (Cf) Cf[o] = v;
                if (Cb) Cb[o] = f2b(v);
            }
        }
    }
}

// ---------------- conv: 128px (2 rows x 64) x 64 OC, B through LDS (double buffer) ----------------
// pimg: padded [206][208][ICP] bf16 (3px frame, zeroed)
// wT: [KS*KS][OCtot][ICP] bf16 ; out: [40000][OCtot] fp32
template <int KS, int ICP>
__global__ __launch_bounds__(256) void conv5_mfma_k(
        const u16* __restrict__ pimg, const u16* __restrict__ wT,
        float* __restrict__ out, int OCtot) {
    constexpr int PAD = KS / 2;
    constexpr int WIN = 64 + KS - 1;
    constexpr int STR = ICP + 8;
    constexpr int KSTEPS = ICP / 32;
    constexpr int NTAP = KS * KS;
    constexpr int ACH = WIN * (ICP / 8);   // uint4 per A row-window
    constexpr int NB = ICP / 32;           // B uint4 chunks per thread per tap
    __shared__ u16 As[2 * WIN * STR];
    __shared__ u16 Bs[2 * 64 * STR];
    const int bx = blockIdx.x;
    const int yp = (bx >> 2) * 2;          // output rows yp, yp+1
    const int xc = bx & 3;
    const int x0 = (xc == 3) ? 136 : xc * 64;
    const int n0 = blockIdx.y * 64;
    const int t = threadIdx.x;
    const int wave = t >> 6, lane = t & 63;
    const int row = wave >> 1;             // which output row
    const int wn = (wave & 1) * 32;
    const int lr = lane & 15, lkq = lane >> 4, lk = lkq * 8;

    f32x4 acc[4][2] = {};
    const u16* wbase = wT + (size_t)n0 * ICP;

    uint4 breg[NB];
    int bro[NB], bco[NB];
#pragma unroll
    for (int k = 0; k < NB; k++) {
        int ci = t + k * 256;
        bro[k] = ci / (ICP / 8);
        bco[k] = ci - bro[k] * (ICP / 8);
    }
    // prefetch tap 0 into Bs[0]
#pragma unroll
    for (int k = 0; k < NB; k++)
        breg[k] = *(const uint4*)&wbase[(size_t)bro[k] * ICP + bco[k] * 8];
#pragma unroll
    for (int k = 0; k < NB; k++)
        *(uint4*)&Bs[(size_t)bro[k] * STR + bco[k] * 8] = breg[k];

    for (int ky = 0; ky < KS; ky++) {
        __syncthreads();   // previous taps done reading As
        {
            const u16* s0 = pimg + (((size_t)(yp + ky + 3 - PAD)) * 208 + (x0 + 3 - PAD)) * ICP;
            const u16* s1 = pimg + (((size_t)(yp + 1 + ky + 3 - PAD)) * 208 + (x0 + 3 - PAD)) * ICP;
            for (int ci = t; ci < 2 * ACH; ci += 256) {
                int w2 = ci / ACH, rem = ci - w2 * ACH;
                int r = rem / (ICP / 8), c = rem - r * (ICP / 8);
                const u16* s = w2 ? s1 : s0;
                *(uint4*)&As[(size_t)(w2 * WIN + r) * STR + c * 8] =
                    *(const uint4*)&s[(size_t)r * ICP + c * 8];
            }
        }
        for (int kx = 0; kx < KS; kx++) {
            const int tap = ky * KS + kx;
            __syncthreads();   // As + Bs[tap&1] visible; prev compute done
            if (tap + 1 < NTAP) {
                const u16* ws = wbase + (size_t)(tap + 1) * OCtot * ICP;
#pragma unroll
                for (int k = 0; k < NB; k++)
                    breg[k] = *(const uint4*)&ws[(size_t)bro[k] * ICP + bco[k] * 8];
            }
            const u16* ab = &As[((size_t)row * WIN + kx) * STR];
            const u16* bb = &Bs[(size_t)((tap & 1) * 64 + wn) * STR];
#pragma unroll
            for (int ks = 0; ks < KSTEPS; ks++) {
                bf16x8 b0 = *(const bf16x8*)&bb[(size_t)lr * STR + ks * 32 + lk];
                bf16x8 b1 = *(const bf16x8*)&bb[(size_t)(lr + 16) * STR + ks * 32 + lk];
#pragma unroll
                for (int i = 0; i < 4; i++) {
                    bf16x8 a = *(const bf16x8*)&ab[(size_t)(lr + i * 16) * STR + ks * 32 + lk];
                    acc[i][0] = __builtin_amdgcn_mfma_f32_16x16x32_bf16(a, b0, acc[i][0], 0, 0, 0);
                    acc[i][1] = __builtin_amdgcn_mfma_f32_16x16x32_bf16(a, b1, acc[i][1], 0, 0, 0);
                }
            }
            if (tap + 1 < NTAP) {
                u16* bd = &Bs[(size_t)(((tap + 1) & 1) * 64) * STR];
#pragma unroll
                for (int k = 0; k < NB; k++)
                    *(uint4*)&bd[(size_t)bro[k] * STR + bco[k] * 8] = breg[k];
            }
        }
    }
    const int px0 = (yp + row) * 200 + x0;
#pragma unroll
    for (int i = 0; i < 4; i++) {
#pragma unroll
        for (int j = 0; j < 2; j++) {
#pragma unroll
            for (int r = 0; r < 4; r++) {
                int ml = i * 16 + lkq * 4 + r;
                int nl = wn + j * 16 + lr;
                out[(size_t)(px0 + ml) * OCtot + n0 + nl] = acc[i][j][r];
            }
        }
    }
}

// ---------------- deformable sampling: 2 queries per wave, uint2 gathers ----------------
__global__ __launch_bounds__(256) void deform3_k(
        const u16* __restrict__ v, const u16* __restrict__ oa,
        u16* __restrict__ outb, int q0, int nq) {
    const int t = threadIdx.x;
    const int wq = t >> 6;
    const int lane = t & 63;
    const int s = lane >> 5;
    const int l32 = lane & 31;
    const int h = l32 >> 2;
    const int cl = l32 & 3;
    const int qi = blockIdx.x * 8 + wq * 2 + s;
    if (qi >= nq) return;
    const int gq = q0 + qi;
    const float rx = ((gq % 200) + 0.5f) / 200.f;
    const float ry = ((gq / 200) + 0.5f) / 200.f;

    const uint* lp = (const uint*)(oa + (size_t)qi * 768 + 512 + h * 32);
    float lg[32];
#pragma unroll
    for (int i = 0; i < 16; i++) { uint u = lp[i]; lg[2 * i] = blo(u); lg[2 * i + 1] = bhi(u); }
    float mx = -1e30f;
#pragma unroll
    for (int i = 0; i < 32; i++) mx = fmaxf(mx, lg[i]);
    float ssum = 0.f;
#pragma unroll
    for (int i = 0; i < 32; i++) { lg[i] = __expf(lg[i] - mx); ssum += lg[i]; }
    const float inv = 1.f / ssum;

    const uint* op = (const uint*)(oa + (size_t)qi * 768 + h * 64);

    const int HS[4] = {128, 64, 32, 16};
    const int WS[4] = {256, 128, 64, 32};
    const int ST[4] = {0, 32768, 40960, 43008};
    float a0 = 0.f, a1 = 0.f, a2 = 0.f, a3 = 0.f;
#pragma unroll
    for (int l = 0; l < 4; l++) {
        const int H = HS[l], W = WS[l];
        const float fW = (float)W, fH = (float)H;
        const u16* vb = v + (size_t)ST[l] * 128 + h * 16 + cl * 4;
#pragma unroll
        for (int p = 0; p < 8; p++) {
            uint pr = op[l * 8 + p];
            float ox = blo(pr), oy = bhi(pr);
            float xx = rx * fW + ox - 0.5f;
            float yy = ry * fH + oy - 0.5f;
            float xf = floorf(xx), yf = floorf(yy);
            int ix = (int)xf, iy = (int)yf;
            float fx = xx - xf, fy = yy - yf;
            float aw = lg[l * 8 + p] * inv;
            int x1 = ix + 1, y1 = iy + 1;
            bool vx0 = (unsigned)ix < (unsigned)W;
            bool vx1 = (unsigned)x1 < (unsigned)W;
            bool vy0 = (unsigned)iy < (unsigned)H;
            bool vy1 = (unsigned)y1 < (unsigned)H;
            int cx0 = min(max(ix, 0), W - 1), cx1 = min(max(x1, 0), W - 1);
            int cy0 = min(max(iy, 0), H - 1), cy1 = min(max(y1, 0), H - 1);
            float w00 = (vx0 && vy0) ? (1.f - fx) * (1.f - fy) * aw : 0.f;
            float w10 = (vx1 && vy0) ? fx * (1.f - fy) * aw : 0.f;
            float w01 = (vx0 && vy1) ? (1.f - fx) * fy * aw : 0.f;
            float w11 = (vx1 && vy1) ? fx * fy * aw : 0.f;
            uint2 u00 = *(const uint2*)(vb + (size_t)(cy0 * W + cx0) * 128);
            uint2 u10 = *(const uint2*)(vb + (size_t)(cy0 * W + cx1) * 128);
            uint2 u01 = *(const uint2*)(vb + (size_t)(cy1 * W + cx0) * 128);
            uint2 u11 = *(const uint2*)(vb + (size_t)(cy1 * W + cx1) * 128);
            a0 = fmaf(w00, blo(u00.x), a0); a1 = fmaf(w00, bhi(u00.x), a1);
            a2 = fmaf(w00, blo(u00.y), a2); a3 = fmaf(w00, bhi(u00.y), a3);
            a0 = fmaf(w10, blo(u10.x), a0); a1 = fmaf(w10, bhi(u10.x), a1);
            a2 = fmaf(w10, blo(u10.y), a2); a3 = fmaf(w10, bhi(u10.y), a3);
            a0 = fmaf(w01, blo(u01.x), a0); a1 = fmaf(w01, bhi(u01.x), a1);
            a2 = fmaf(w01, blo(u01.y), a2); a3 = fmaf(w01, bhi(u01.y), a3);
            a0 = fmaf(w11, blo(u11.x), a0); a1 = fmaf(w11, bhi(u11.x), a1);
            a2 = fmaf(w11, blo(u11.y), a2); a3 = fmaf(w11, bhi(u11.y), a3);
        }
    }
    uint2 o;
    o.x = (uint)f2b(a0) | ((uint)f2b(a1) << 16);
    o.y = (uint)f2b(a2) | ((uint)f2b(a3) << 16);
    *(uint2*)(outb + (size_t)gq * 128 + h * 16 + cl * 4) = o;
}

// ---------------- fused residual + layernorm ----------------
__global__ __launch_bounds__(256) void add_ln_k(
        float* __restrict__ q, const float* __restrict__ a,
        const float* __restrict__ g, const float* __restrict__ b,
        u16* __restrict__ qb) {
    const int row = blockIdx.x * 4 + (threadIdx.x >> 6);
    const int lane = threadIdx.x & 63;
    float s0 = q[(size_t)row * 128 + lane] + a[(size_t)row * 128 + lane];
    float s1 = q[(size_t)row * 128 + 64 + lane] + a[(size_t)row * 128 + 64 + lane];
    float sum = s0 + s1;
    for (int o = 32; o > 0; o >>= 1) sum += __shfl_xor(sum, o, 64);
    float mean = sum * (1.f / 128.f);
    float d0 = s0 - mean, d1 = s1 - mean;
    float vs = d0 * d0 + d1 * d1;
    for (int o = 32; o > 0; o >>= 1) vs += __shfl_xor(vs, o, 64);
    float inv = rsqrtf(vs * (1.f / 128.f) + 1e-5f);
    float o0 = d0 * inv * g[lane] + b[lane];
    float o1 = d1 * inv * g[64 + lane] + b[64 + lane];
    q[(size_t)row * 128 + lane] = o0;
    q[(size_t)row * 128 + 64 + lane] = o1;
    qb[(size_t)row * 128 + lane] = f2b(o0);
    qb[(size_t)row * 128 + 64 + lane] = f2b(o1);
}

// ---------------- pimg fill from qb (128 ch), covers borders with zero ----------------
__global__ void fill_pimg2_k(const u16* __restrict__ qb, u16* __restrict__ pimg) {
    int i = blockIdx.x * 256 + threadIdx.x;   // over 206*208*16 uint4
    if (i >= 685568) return;
    int pp = i >> 4, c8 = i & 15;
    int py = pp / 208, px = pp - py * 208;
    uint4 val = {0u, 0u, 0u, 0u};
    if (py >= 3 && py < 203 && px >= 3 && px < 203)
        val = ((const uint4*)qb)[((size_t)((py - 3) * 200 + (px - 3))) * 16 + c8];
    ((uint4*)pimg)[i] = val;
}

// ---------------- BN stats + apply ----------------
__global__ __launch_bounds__(256) void bn_stats2_k(const float* __restrict__ x,
                                                   float* __restrict__ acc,
                                                   int cSh, int ppb) {
    const int t = threadIdx.x;
    const int Cp = 1 << cSh;
    const int c = t & (Cp - 1);
    const int sub = t >> cSh;
    const int nsub = 256 >> cSh;
    float s = 0.f, s2 = 0.f;
    const int pbase = blockIdx.x * ppb;
    for (int i = sub; i < ppb; i += nsub) {
        float v = x[(size_t)(pbase + i) * Cp + c];
        s += v; s2 += v * v;
    }
    __shared__ float ls[256], ls2[256];
    ls[t] = s; ls2[t] = s2;
    __syncthreads();
    if (t < Cp) {
        for (int k = 1; k < nsub; k++) { s += ls[t + k * Cp]; s2 += ls2[t + k * Cp]; }
        atomicAdd(&acc[2 * t], s);
        atomicAdd(&acc[2 * t + 1], s2);
    }
}

__global__ void bn_fin_k(const float* __restrict__ acc, float* __restrict__ mv, int C) {
    int t = threadIdx.x;
    if (t >= C) return;
    float m = acc[2 * t] * (1.f / 40000.f);
    float var = acc[2 * t + 1] * (1.f / 40000.f) - m * m;
    mv[2 * t] = m;
    mv[2 * t + 1] = rsqrtf(var + 1e-5f);
}

// apply into padded image layout, writing zeros on borders (no pre-memset needed)
__global__ void bn_apply_pad2_k(const float* __restrict__ x, const float* __restrict__ mv,
                                const float* __restrict__ g, const float* __restrict__ b,
                                u16* __restrict__ outp, int cSh, int Creal) {
    int i = blockIdx.x * 256 + threadIdx.x;
    int Cp = 1 << cSh;
    if (i >= 206 * 208 * Cp) return;
    int c = i & (Cp - 1);
    int pp = i >> cSh;
    int py = pp / 208, px = pp - py * 208;
    float v = 0.f;
    if (c < Creal && py >= 3 && py < 203 && px >= 3 && px < 203) {
        int p = (py - 3) * 200 + (px - 3);
        v = fmaxf((x[(size_t)p * Cp + c] - mv[2 * c]) * mv[2 * c + 1] * g[c] + b[c], 0.f);
    }
    outp[i] = f2b(v);
}

// apply into plain [p][Cp] layout (final stage feeding the 1x1 head)
__global__ void bn_apply2_k(const float* __restrict__ x, const float* __restrict__ mv,
                            const float* __restrict__ g, const float* __restrict__ b,
                            u16* __restrict__ outb, int cSh, int Creal) {
    int i = blockIdx.x * 256 + threadIdx.x;
    int Cp = 1 << cSh;
    if (i >= 40000 * Cp) return;
    int c = i & (Cp - 1);
    float v = 0.f;
    if (c < Creal) v = fmaxf((x[i] - mv[2 * c]) * mv[2 * c + 1] * g[c] + b[c], 0.f);
    outb[i] = f2b(v);
}

// ---------------- 1x1 obj head ----------------
__global__ void obj_conv_k(const u16* __restrict__ in, const float* __restrict__ w,
                           const float* __restrict__ bias, float* __restrict__ out) {
    int p = blockIdx.x * 256 + threadIdx.x;
    if (p >= 40000) return;
    float xin[48];
#pragma unroll
    for (int c = 0; c < 48; c++) xin[c] = b2f(in[(size_t)p * 64 + c]);
    for (int o = 0; o < NCLS; o++) {
        float acc = bias[o];
#pragma unroll
        for (int c = 0; c < 48; c++) acc += xin[c] * w[o * 48 + c];
        out[(size_t)o * 40000 + p] = acc;
    }
}

extern "C" void kernel_launch(void* const* d_in, const int* in_sizes, int n_in,
                              void* d_out, int out_size, void* d_ws, size_t ws_size,
                              hipStream_t stream) {
    const float* value   = (const float*)d_in[0];
    const float* bev_q   = (const float*)d_in[1];
    const float* bev_pos = (const float*)d_in[2];
    const int*   proj    = (const int*)d_in[3];
    const float* Wv      = (const float*)d_in[4];
    const float* bv      = (const float*)d_in[5];
    const float* Woff    = (const float*)d_in[6];
    const float* boff    = (const float*)d_in[7];
    const float* Wattn   = (const float*)d_in[8];
    const float* battn   = (const float*)d_in[9];
    const float* Wout    = (const float*)d_in[10];
    const float* bout    = (const float*)d_in[11];
    const float* Wf1     = (const float*)d_in[12];
    const float* bf1     = (const float*)d_in[13];
    const float* Wf2     = (const float*)d_in[14];
    const float* bf2     = (const float*)d_in[15];
    const float* ln_g    = (const float*)d_in[16];
    const float* ln_b    = (const float*)d_in[17];
    const float* cw1     = (const float*)d_in[18];
    const float* g1      = (const float*)d_in[19];
    const float* b1      = (const float*)d_in[20];
    const float* cw2     = (const float*)d_in[21];
    const float* g2      = (const float*)d_in[22];
    const float* b2      = (const float*)d_in[23];
    const float* cw3     = (const float*)d_in[24];
    const float* g3      = (const float*)d_in[25];
    const float* b3      = (const float*)d_in[26];
    const float* cw4     = (const float*)d_in[27];
    const float* g4      = (const float*)d_in[28];
    const float* b4      = (const float*)d_in[29];
    const float* objw    = (const float*)d_in[30];
    const float* objb    = (const float*)d_in[31];
    float* out = (float*)d_out;

    float* WSb = (float*)d_ws;
    // encoder-stage layout (float-unit offsets)
    float* q     = WSb + 0;                        // 5,120,000
    u16*   qb    = (u16*)(WSb + 5120000);          // 2,560,000 f
    u16*   qpb   = (u16*)(WSb + 7680000);          // 2,560,000 f
    u16*   valb  = (u16*)(WSb + 10240000);         // 2,785,280 f
    u16*   vbufb = (u16*)(WSb + 13025280);         // 2,785,280 f
    u16*   fb    = (u16*)(WSb + 15810560);         // fused off+attn [20032][768] bf16
    float* tmp   = WSb + 18882560;                 // 5,120,000 f (time-disjoint with fb)
    u16*   aob   = (u16*)(WSb + 24002560);         // 2,560,000 f
    u16*   hb    = (u16*)(WSb + 26562560);         // 2,560,000 f
    u16*   wenc  = (u16*)(WSb + 29122560);         // 163,840 f
    u16*   wcv   = (u16*)(WSb + 29286400);         // 475,136 f
    float* bnacc = WSb + 29761536;                 // 512
    float* bnmv  = WSb + 29762048;                 // 256
    int*   maxi  = (int*)(WSb + 29762304);
    float* fbias = WSb + 29762308;                 // 1536

    // conv-stage aliases
    u16*   pimg = (u16*)(WSb + 10240000);          // padded 206x208x128 (over valb)
    float* c1f  = tmp;
    u16*   c1b  = (u16*)(WSb + 13025280);          // padded 206x208x128 (over vbufb)
    float* c2f  = WSb + 0;
    u16*   c2b  = (u16*)(WSb + 5120000);           // padded 206x208x64 (over qb)
    float* c3f  = WSb + 2560000;
    u16*   c3b  = (u16*)(WSb + 7680000);           // padded 206x208x64 (over qpb)
    float* c4f  = WSb + 0;
    u16*   c4b  = (u16*)(WSb + 15810560);          // [40000][64] plain (over fb)

    const size_t L = 163840;
    u16* WvT[2]; u16* WoffT[2]; u16* WoutT[2]; u16* Wf1T[2]; u16* Wf2T[2];
    for (int l = 0; l < 2; l++) {
        u16* base = wenc + l * L;
        WvT[l]    = base;
        WoffT[l]  = base + 16384;   // rows 0..511 = Woff, 512..767 = Wattn
        WoutT[l]  = base + 114688;
        Wf1T[l]   = base + 131072;
        Wf2T[l]   = base + 147456;
    }
    u16* w1T = wcv;
    u16* w2T = wcv + 802816;
    u16* w3T = wcv + 876544;
    u16* w4T = wcv + 913408;

    // ---- mask ----
    hipMemsetAsync(maxi, 0, sizeof(int), stream);
    reduce_max_int<<<157, 256, 0, stream>>>(proj, maxi);
    write_mask<<<157, 256, 0, stream>>>(proj, maxi, out + 840000);

    // ---- weight packing ----
    pack_enc_k<<<1280, 256, 0, stream>>>(Wv, Woff, Wattn, Wout, Wf1, Wf2, wenc);
    pack_bias_k<<<6, 256, 0, stream>>>(boff, battn, fbias);
    pack_cw_k<<<3136, 256, 0, stream>>>(cw1, w1T, 128, 128, 7, 128, 128);
    pack_cw_k<<<288, 256, 0, stream>>>(cw2, w2T, 64, 128, 3, 64, 128);
    pack_cw_k<<<144, 256, 0, stream>>>(cw3, w3T, 48, 64, 3, 64, 64);
    pack_cw_k<<<144, 256, 0, stream>>>(cw4, w4T, 48, 48, 3, 64, 64);
    cvt_b_k<<<2720, 256, 0, stream>>>(value, valb, NVAL * 128 / 8);

    // ---- encoder ----
    hipMemcpyAsync(q, bev_q, (size_t)NQ * EDIM * sizeof(float),
                   hipMemcpyDeviceToDevice, stream);
    const int CH0 = 19968, CH1 = 20032;
    for (int l = 0; l < 2; l++) {
        gemm_mfma_k<<<dim3(680, 2), 256, 0, stream>>>(
            valb, WvT[l], bv + (size_t)l * 128, nullptr, vbufb, 128, 0);
        add2b_k<<<2500, 256, 0, stream>>>(q, bev_pos, qpb, NQ * 128 / 8);
        for (int cidx = 0; cidx < 2; cidx++) {
            int qs = cidx ? CH0 : 0;
            int nq = cidx ? CH1 : CH0;
            gemm_mfma_k<<<dim3(nq / 64, 12), 256, 0, stream>>>(
                qpb + (size_t)qs * 128, WoffT[l], fbias + (size_t)l * 768,
                nullptr, fb, 768, 0);
            deform3_k<<<nq / 8, 256, 0, stream>>>(vbufb, fb, aob, qs, nq);
        }
        gemm_mfma_k<<<dim3(625, 2), 256, 0, stream>>>(
            aob, WoutT[l], bout + (size_t)l * 128, tmp, nullptr, 128, 0);
        add_ln_k<<<10000, 256, 0, stream>>>(q, tmp, ln_g + (size_t)(l * 2 + 0) * 128,
                                            ln_b + (size_t)(l * 2 + 0) * 128, qb);
        gemm_mfma_k<<<dim3(625, 2), 256, 0, stream>>>(
            qb, Wf1T[l], bf1 + (size_t)l * 128, nullptr, hb, 128, 1);
        gemm_mfma_k<<<dim3(625, 2), 256, 0, stream>>>(
            hb, Wf2T[l], bf2 + (size_t)l * 128, tmp, nullptr, 128, 0);
        add_ln_k<<<10000, 256, 0, stream>>>(q, tmp, ln_g + (size_t)(l * 2 + 1) * 128,
                                            ln_b + (size_t)(l * 2 + 1) * 128, qb);
    }

    // ---- conv head ----
    fill_pimg2_k<<<2678, 256, 0, stream>>>(qb, pimg);

    conv5_mfma_k<7, 128><<<dim3(400, 2), 256, 0, stream>>>(pimg, w1T, c1f, 128);
    hipMemsetAsync(bnacc, 0, 512 * sizeof(float), stream);
    bn_stats2_k<<<125, 256, 0, stream>>>(c1f, bnacc, 7, 320);
    bn_fin_k<<<1, 128, 0, stream>>>(bnacc, bnmv, 128);
    bn_apply_pad2_k<<<21424, 256, 0, stream>>>(c1f, bnmv, g1, b1, c1b, 7, 128);

    conv5_mfma_k<3, 128><<<dim3(400, 1), 256, 0, stream>>>(c1b, w2T, c2f, 64);
    hipMemsetAsync(bnacc, 0, 512 * sizeof(float), stream);
    bn_stats2_k<<<125, 256, 0, stream>>>(c2f, bnacc, 6, 320);
    bn_fin_k<<<1, 64, 0, stream>>>(bnacc, bnmv, 64);
    bn_apply_pad2_k<<<10712, 256, 0, stream>>>(c2f, bnmv, g2, b2, c2b, 6, 64);

    conv5_mfma_k<3, 64><<<dim3(400, 1), 256, 0, stream>>>(c2b, w3T, c3f, 64);
    hipMemsetAsync(bnacc, 0, 512 * sizeof(float), stream);
    bn_stats2_k<<<125, 256, 0, stream>>>(c3f, bnacc, 6, 320);
    bn_fin_k<<<1, 48, 0, stream>>>(bnacc, bnmv, 48);
    bn_apply_pad2_k<<<10712, 256, 0, stream>>>(c3f, bnmv, g3, b3, c3b, 6, 48);

    conv5_mfma_k<3, 64><<<dim3(400, 1), 256, 0, stream>>>(c3b, w4T, c4f, 64);
    hipMemsetAsync(bnacc, 0, 512 * sizeof(float), stream);
    bn_stats2_k<<<125, 256, 0, stream>>>(c4f, bnacc, 6, 320);
    bn_fin_k<<<1, 48, 0, stream>>>(bnacc, bnmv, 48);
    bn_apply2_k<<<10000, 256, 0, stream>>>(c4f, bnmv, g4, b4, c4b, 6, 48);

    obj_conv_k<<<157, 256, 0, stream>>>(c4b, objw, objb, out);
}